// Round 1
// baseline (1474.898 us; speedup 1.0000x reference)
//
#include <hip/hip_runtime.h>

#define D_DIM 2560
#define T_DIM 4096
#define B_DIM 4
#define H_DIM 10
#define DH 256
#define TW_DIM 4
#define M_DIM (B_DIM * T_DIM)   // 16384
#define CHUNKS 64
#define TC (T_DIM / CHUNKS)     // 64

typedef _Float16 f16;
typedef __attribute__((ext_vector_type(8))) _Float16 f16x8;
typedef __attribute__((ext_vector_type(4))) _Float16 f16x4;
typedef __attribute__((ext_vector_type(2))) _Float16 f16x2;
typedef __attribute__((ext_vector_type(4))) float f32x4;
typedef __attribute__((ext_vector_type(2))) float f32x2;

// ---------------- convert f32 -> f16 (vectorized x4) ----------------
__global__ void cvt_f16_kernel(const float* __restrict__ in, f16* __restrict__ out, long n4) {
  long i = (long)blockIdx.x * blockDim.x + threadIdx.x;
  if (i >= n4) return;
  f32x4 v = ((const f32x4*)in)[i];
  f16x4 o;
  o[0] = (f16)v[0]; o[1] = (f16)v[1]; o[2] = (f16)v[2]; o[3] = (f16)v[3];
  ((f16x4*)out)[i] = o;
}

// ---------------- transpose + convert, 3 separate square sources ----------------
__global__ void transpose_cvt3_kernel(const float* __restrict__ s0, const float* __restrict__ s1,
                                      const float* __restrict__ s2, f16* __restrict__ out,
                                      int R, int C) {
  __shared__ float tile[32][33];
  const int z = blockIdx.z;
  const float* in = (z == 0) ? s0 : ((z == 1) ? s1 : s2);
  out += (long)z * R * C;
  int c0 = blockIdx.x * 32, r0 = blockIdx.y * 32;
  int tx = threadIdx.x, ty = threadIdx.y;
  for (int i = ty; i < 32; i += 8)
    tile[i][tx] = in[(long)(r0 + i) * C + (c0 + tx)];
  __syncthreads();
  for (int i = ty; i < 32; i += 8)
    out[(long)(c0 + i) * R + (r0 + tx)] = (f16)tile[tx][i];
}

// ---------------- transpose + convert, 2 batched sources (ig, ag) ----------------
__global__ void transpose_cvt2_kernel(const float* __restrict__ sa, const float* __restrict__ sb,
                                      f16* __restrict__ out, int R, int C, int half) {
  __shared__ float tile[32][33];
  const int z = blockIdx.z;
  const float* in = (z < half) ? (sa + (long)z * R * C) : (sb + (long)(z - half) * R * C);
  out += (long)z * R * C;
  int c0 = blockIdx.x * 32, r0 = blockIdx.y * 32;
  int tx = threadIdx.x, ty = threadIdx.y;
  for (int i = ty; i < 32; i += 8)
    tile[i][tx] = in[(long)(r0 + i) * C + (c0 + tx)];
  __syncthreads();
  for (int i = ty; i < 32; i += 8)
    out[(long)(c0 + i) * R + (r0 + tx)] = (f16)tile[tx][i];
}

// ---------------- async global -> LDS, 16B per lane ----------------
__device__ __forceinline__ void async_cp16(const void* g, void* l) {
  __builtin_amdgcn_global_load_lds(
      (const __attribute__((address_space(1))) unsigned int*)g,
      (__attribute__((address_space(3))) unsigned int*)l, 16, 0, 0);
}

__device__ __forceinline__ float fast_sigmoid(float v) {
  return 1.f / (1.f + __expf(-v));
}

// =====================================================================
// NEW: 256x256 tile, BK=32, 4-deep LDS ring, counted vmcnt(8), 1 barrier
// per K-tile, setprio around MFMA clusters. 512 threads = 8 waves (2x4),
// per-wave 128x64 output (acc[8][4]). LDS = 4 * 32KB = 128 KiB.
//
// Pipeline invariant (loads retire in issue order):
//   tile k staged with calls 4k+1..4k+4 per thread (prologue tiles 0..2,
//   iteration t stages tile t+3, clamped+duplicated at tail so counts
//   stay uniform). At end of iter t: issued = 4t+16, vmcnt(8) retires
//   4t+8 = all calls of tiles 0..t+1  => tile t+1 resident before iter t+1.
//   WAR: iter t stages into buf[(t+3)&3] which held tile t-1, fully read
//   before the end-of-(t-1) barrier that precedes these issues.
// =====================================================================
#define BM2 256
#define BN2 256
#define BK2 32

template<int ACT, int OUT16>
__global__ __launch_bounds__(512, 2)
void gemm256_kernel(const f16* __restrict__ A, long ldA,
                    const f16* __restrict__ Bt, long ldB,
                    const float* __restrict__ bias,
                    void* __restrict__ Cv, long ldC, int K) {
  // 4 buffers; per buffer: A-tile 8192 halfs (256r x 32k) then B-tile 8192
  __shared__ __attribute__((aligned(16))) f16 sm[4 * 16384];
  const int tid = threadIdx.x;
  const int wave = tid >> 6;
  const int lane = tid & 63;
  const int wm = wave >> 2;      // 0..1 -> rows wm*128..+127
  const int wn = wave & 3;       // 0..3 -> cols wn*64..+63
  const long bm = (long)blockIdx.y * BM2;
  const long bn = (long)blockIdx.x * BN2;

  // ---- staging geometry: unit = 128 rows x 64B (8KB); wave covers 16 rows
  const int sRow = wave * 16 + (lane >> 2);            // row within unit
  const int sChunk = (lane & 3) ^ ((lane >> 2) & 3);   // XOR swizzle (store)
  const int sOff = sChunk * 8;                          // halfs
  const f16* pA0 = A + (bm + sRow) * ldA + sOff;        // rows 0..127
  const f16* pA1 = pA0 + 128 * ldA;                     // rows 128..255
  const f16* pB0 = Bt + (bn + sRow) * ldB + sOff;
  const f16* pB1 = pB0 + 128 * ldB;
  const int wOff = wave * 512;                          // halfs within unit

  // ---- fragment-read geometry (reader compensates store swizzle)
  const int quad = lane >> 4, l16 = lane & 15;
  const int rswz = (quad ^ (l16 & 3)) * 8;
  const int aRowBase = (wm * 128 + l16) * BK2 + rswz;   // + i*16*BK2
  const int bRowBase = (wn * 64 + l16) * BK2 + rswz;    // + j*16*BK2

  f32x4 acc[8][4];
#pragma unroll
  for (int i = 0; i < 8; ++i)
#pragma unroll
    for (int j = 0; j < 4; ++j) {
      acc[i][j][0] = 0.f; acc[i][j][1] = 0.f; acc[i][j][2] = 0.f; acc[i][j][3] = 0.f;
    }

  const int NT = K / BK2;

  // ---- prologue: stage tiles 0,1,2 (12 calls/thread), land tile 0
#pragma unroll
  for (int p = 0; p < 3; ++p) {
    f16* dst = sm + p * 16384;
    const int kp = (p < NT ? p : NT - 1) * BK2;
    async_cp16(pA0 + kp, dst + wOff);
    async_cp16(pA1 + kp, dst + 4096 + wOff);
    async_cp16(pB0 + kp, dst + 8192 + wOff);
    async_cp16(pB1 + kp, dst + 12288 + wOff);
  }
  asm volatile("s_waitcnt vmcnt(8)" ::: "memory");  // tile 0 resident
  __builtin_amdgcn_s_barrier();

  // ---- main loop: 2 phases per K-tile, 16 MFMA each
#pragma unroll 4
  for (int t = 0; t < NT; ++t) {
    const f16* As = sm + (t & 3) * 16384;
    const f16* Bs = As + 8192;
    const int kp = (t + 3 < NT ? t + 3 : NT - 1) * BK2;   // clamped prefetch
    f16* dst = sm + ((t + 3) & 3) * 16384;

    // phase 0: rows wm*128+0..63
    f16x8 af0[4], bf[4];
#pragma unroll
    for (int i = 0; i < 4; ++i) af0[i] = *(const f16x8*)&As[aRowBase + i * 16 * BK2];
#pragma unroll
    for (int j = 0; j < 4; ++j) bf[j]  = *(const f16x8*)&Bs[bRowBase + j * 16 * BK2];
    async_cp16(pA0 + kp, dst + wOff);
    async_cp16(pA1 + kp, dst + 4096 + wOff);
    __builtin_amdgcn_s_setprio(1);
#pragma unroll
    for (int i = 0; i < 4; ++i)
#pragma unroll
      for (int j = 0; j < 4; ++j)
        acc[i][j] = __builtin_amdgcn_mfma_f32_16x16x32_f16(af0[i], bf[j], acc[i][j], 0, 0, 0);
    __builtin_amdgcn_s_setprio(0);

    // phase 1: rows wm*128+64..127 (bf reused)
    f16x8 af1[4];
#pragma unroll
    for (int i = 0; i < 4; ++i) af1[i] = *(const f16x8*)&As[aRowBase + (64 + i * 16) * BK2];
    async_cp16(pB0 + kp, dst + 8192 + wOff);
    async_cp16(pB1 + kp, dst + 12288 + wOff);
    __builtin_amdgcn_s_setprio(1);
#pragma unroll
    for (int i = 0; i < 4; ++i)
#pragma unroll
      for (int j = 0; j < 4; ++j)
        acc[4 + i][j] = __builtin_amdgcn_mfma_f32_16x16x32_f16(af1[i], bf[j], acc[4 + i][j], 0, 0, 0);
    __builtin_amdgcn_s_setprio(0);

    asm volatile("s_waitcnt vmcnt(8)" ::: "memory");  // tile t+1 resident
    __builtin_amdgcn_s_barrier();
  }

  // ---- epilogue: C/D layout col=lane&15, row=(lane>>4)*4+reg
#pragma unroll
  for (int i = 0; i < 8; ++i) {
    const long row0 = bm + wm * 128 + i * 16 + quad * 4;
#pragma unroll
    for (int j = 0; j < 4; ++j) {
      const long colIn = bn + wn * 64 + j * 16 + l16;
      const float bv = bias[colIn];
#pragma unroll
      for (int r = 0; r < 4; ++r) {
        const long row = row0 + r;
        float v = acc[i][j][r] + bv;
        if (ACT == 1) {
          const float u = v;
          const float tt = 0.7978845608028654f * (u + 0.044715f * u * u * u);
          v = u * fast_sigmoid(2.f * tt);   // gelu tanh approx
        }
        const long cidx = row * ldC + colIn;
        if (OUT16) ((f16*)Cv)[cidx] = (f16)v;
        else       ((float*)Cv)[cidx] = v;
      }
    }
  }
}

// ---------------- m97-style 128^2 GEMM (kept for block-diag gate GEMMs) ----------------
// ACT: 2=sigmoid, 3=sigmoid + fused RG-LRU elementwise.
#define BM 128
#define BN 128
#define BK 32

template<int ACT, int OUT16>
__global__ __launch_bounds__(256, 2)
void gemm_kernel(const f16* __restrict__ A, long ldA, long zA,
                 const f16* __restrict__ Bt, long zB,
                 const float* __restrict__ bias, long zBias,
                 void* __restrict__ Cv, long ldC, long zC, int K,
                 const f16* __restrict__ cX, const f16* __restrict__ gX,
                 const float* __restrict__ apar, const int* __restrict__ segp,
                 f16* __restrict__ nxOut) {
  __shared__ __attribute__((aligned(16))) f16 As[BM * BK];
  __shared__ __attribute__((aligned(16))) f16 Bs[BN * BK];
  const int tid = threadIdx.x;
  const int wave = tid >> 6;
  const int lane = tid & 63;
  const int wm = wave >> 1, wn = wave & 1;
  const long bm = (long)blockIdx.y * BM;
  const long bn = (long)blockIdx.x * BN;
  const int z = blockIdx.z;
  A += (long)z * zA;
  Bt += (long)z * zB;
  bias += (long)z * zBias;
  const long cColOff = (long)z * zC;

  const int sRow = wave * 32 + (lane >> 2);
  const int sCol = (((lane & 3) ^ (sRow & 3)) * 8);  // halfs
  const f16* gA = A + (bm + sRow) * ldA + sCol;
  const f16* gB = Bt + (bn + sRow) * (long)K + sCol;
  f16* lA = As + wave * 1024;
  f16* lB = Bs + wave * 1024;

  f32x4 acc[4][4];
#pragma unroll
  for (int i = 0; i < 4; ++i)
#pragma unroll
    for (int j = 0; j < 4; ++j) {
      acc[i][j][0] = 0.f; acc[i][j][1] = 0.f; acc[i][j][2] = 0.f; acc[i][j][3] = 0.f;
    }

  const int quad = lane >> 4, l16 = lane & 15;
  const int rswz = (quad ^ (l16 & 3)) * 8;

  for (int k0 = 0; k0 < K; k0 += BK) {
    async_cp16(gA, lA);
    async_cp16(gA + 16 * ldA, lA + 512);
    async_cp16(gB, lB);
    async_cp16(gB + 16 * (long)K, lB + 512);
    gA += BK; gB += BK;
    __syncthreads();
    f16x8 af[4], bf[4];
#pragma unroll
    for (int i = 0; i < 4; ++i) {
      af[i] = *(const f16x8*)&As[(wm * 64 + i * 16 + l16) * BK + rswz];
      bf[i] = *(const f16x8*)&Bs[(wn * 64 + i * 16 + l16) * BK + rswz];
    }
#pragma unroll
    for (int i = 0; i < 4; ++i)
#pragma unroll
      for (int j = 0; j < 4; ++j)
        acc[i][j] = __builtin_amdgcn_mfma_f32_16x16x32_f16(af[i], bf[j], acc[i][j], 0, 0, 0);
    __syncthreads();
  }

#pragma unroll
  for (int i = 0; i < 4; ++i) {
    const long row0 = bm + wm * 64 + i * 16 + quad * 4;
#pragma unroll
    for (int j = 0; j < 4; ++j) {
      const long colIn = bn + wn * 64 + j * 16 + l16;
      const long colG = cColOff + colIn;
      const float bv = bias[colIn];
      float sp = 0.f;
      if (ACT == 3) sp = log1pf(__expf(apar[colG]));
#pragma unroll
      for (int r = 0; r < 4; ++r) {
        const long row = row0 + r;
        float v = acc[i][j][r] + bv;
        if (ACT == 1) {
          const float u = v;
          const float t = 0.7978845608028654f * (u + 0.044715f * u * u * u);
          v = u * fast_sigmoid(2.f * t);
        } else if (ACT == 2) {
          v = fast_sigmoid(v);
        }
        const long cidx = row * ldC + colG;
        if (ACT == 3) {
          const float ga = fast_sigmoid(v);
          const float log_a = -8.f * ga * sp;
          float a = __expf(log_a);
          float mult = sqrtf(fmaxf(1.f - __expf(2.f * log_a), 0.f));
          if (segp[row] == 0) { a = 0.f; mult = 1.f; }
          const float nx = (float)cX[cidx] * (float)gX[cidx] * mult;
          ((f16*)Cv)[cidx] = (f16)a;
          nxOut[cidx] = (f16)nx;
        } else if (OUT16) {
          ((f16*)Cv)[cidx] = (f16)v;
        } else {
          ((float*)Cv)[cidx] = v;
        }
      }
    }
  }
}

// ---------------- causal depthwise conv (TW=4), f16 in -> f16 out, x4 ----------------
__global__ void conv_kernel(const f16* __restrict__ xb, const float* __restrict__ cw,
                            const float* __restrict__ cb, f16* __restrict__ out) {
  const int d4 = blockIdx.x * 128 + threadIdx.x;  // over D/4 = 640
  const int t = blockIdx.y;
  const int b = blockIdx.z;
  const long idx4 = ((long)b * T_DIM + t) * (D_DIM / 4) + d4;
  f32x4 acc = ((const f32x4*)cb)[d4];
#pragma unroll
  for (int i = 0; i < TW_DIM; ++i) {
    const int tt = t - (TW_DIM - 1) + i;
    if (tt >= 0) {
      f16x4 xv = ((const f16x4*)xb)[idx4 + (long)(i - (TW_DIM - 1)) * (D_DIM / 4)];
      f32x4 w = ((const f32x4*)cw)[i * (D_DIM / 4) + d4];
      acc[0] += w[0] * (float)xv[0];
      acc[1] += w[1] * (float)xv[1];
      acc[2] += w[2] * (float)xv[2];
      acc[3] += w[3] * (float)xv[3];
    }
  }
  f16x4 o;
  o[0] = (f16)acc[0]; o[1] = (f16)acc[1]; o[2] = (f16)acc[2]; o[3] = (f16)acc[3];
  ((f16x4*)out)[idx4] = o;
}

// ---------------- chunked scan: h_t = a_t h_{t-1} + x_t (x2 vectorized) ----------------
__global__ void scanA_kernel(const f16* __restrict__ a16, const f16* __restrict__ nx16,
                             float* __restrict__ Ac, float* __restrict__ Sc) {
  const int d2 = blockIdx.x * 256 + threadIdx.x;  // over D/2 = 1280
  const int c = blockIdx.y;
  const int b = blockIdx.z;
  long base2 = ((long)b * T_DIM + (long)c * TC) * (D_DIM / 2) + d2;
  float Ap0 = 1.f, Ap1 = 1.f, S0 = 0.f, S1 = 0.f;
  for (int t = 0; t < TC; ++t) {
    f16x2 av = ((const f16x2*)a16)[base2];
    f16x2 xv = ((const f16x2*)nx16)[base2];
    S0 = (float)av[0] * S0 + (float)xv[0];
    S1 = (float)av[1] * S1 + (float)xv[1];
    Ap0 *= (float)av[0];
    Ap1 *= (float)av[1];
    base2 += D_DIM / 2;
  }
  const long cidx2 = ((long)b * CHUNKS + c) * (D_DIM / 2) + d2;
  f32x2 av_; av_[0] = Ap0; av_[1] = Ap1;
  f32x2 sv_; sv_[0] = S0; sv_[1] = S1;
  ((f32x2*)Ac)[cidx2] = av_;
  ((f32x2*)Sc)[cidx2] = sv_;
}

__global__ void scanB_kernel(const float* __restrict__ Ac, const float* __restrict__ Sc,
                             float* __restrict__ He) {
  const int d = blockIdx.x * 256 + threadIdx.x;
  const int b = blockIdx.z;
  float h = 0.f;
  for (int c = 0; c < CHUNKS; ++c) {
    const long cidx = ((long)b * CHUNKS + c) * D_DIM + d;
    He[cidx] = h;  // h at entry of chunk c
    h = Ac[cidx] * h + Sc[cidx];
  }
}

__global__ void scanC_kernel(const f16* __restrict__ a16, const f16* __restrict__ nx16,
                             const float* __restrict__ He, const f16* __restrict__ y16,
                             f16* __restrict__ hy16) {
  const int d2 = blockIdx.x * 256 + threadIdx.x;
  const int c = blockIdx.y;
  const int b = blockIdx.z;
  long base2 = ((long)b * T_DIM + (long)c * TC) * (D_DIM / 2) + d2;
  f32x2 hv = ((const f32x2*)He)[((long)b * CHUNKS + c) * (D_DIM / 2) + d2];
  float h0 = hv[0], h1 = hv[1];
  for (int t = 0; t < TC; ++t) {
    f16x2 av = ((const f16x2*)a16)[base2];
    f16x2 xv = ((const f16x2*)nx16)[base2];
    f16x2 yv = ((const f16x2*)y16)[base2];
    h0 = (float)av[0] * h0 + (float)xv[0];
    h1 = (float)av[1] * h1 + (float)xv[1];
    f16x2 o;
    o[0] = (f16)(h0 * (float)yv[0]);
    o[1] = (f16)(h1 * (float)yv[1]);
    ((f16x2*)hy16)[base2] = o;
    base2 += D_DIM / 2;
  }
}

// ---------------- launch ----------------
extern "C" void kernel_launch(void* const* d_in, const int* in_sizes, int n_in,
                              void* d_out, int out_size, void* d_ws, size_t ws_size,
                              hipStream_t stream) {
  const float* x   = (const float*)d_in[0];
  const int*   segp= (const int*)d_in[1];
  const float* Wy  = (const float*)d_in[2];
  const float* by  = (const float*)d_in[3];
  const float* Wx  = (const float*)d_in[4];
  const float* bx  = (const float*)d_in[5];
  const float* cw  = (const float*)d_in[6];
  const float* cb  = (const float*)d_in[7];
  const float* ap  = (const float*)d_in[8];
  const float* igw = (const float*)d_in[9];
  const float* igb = (const float*)d_in[10];
  const float* agw = (const float*)d_in[11];
  const float* agb = (const float*)d_in[12];
  const float* Wo  = (const float*)d_in[13];
  const float* bo  = (const float*)d_in[14];
  float* out = (float*)d_out;
  char* ws = (char*)d_ws;

  const long MD = (long)M_DIM * D_DIM;  // 41,943,040
  f16*   x16    = (f16*)(ws + 0);          // dead after GEMMs 1,2 -> a16
  f16*   a16    = (f16*)(ws + 0);
  f16*   y16    = (f16*)(ws + MD * 2);     // live until scanC
  f16*   xb2    = (f16*)(ws + MD * 4);     // dead after conv -> gx16 -> hy16
  f16*   gx16   = (f16*)(ws + MD * 4);
  f16*   hy16   = (f16*)(ws + MD * 4);
  f16*   conv16 = (f16*)(ws + MD * 6);     // live until ag-gate epilogue
  f16*   nx16   = (f16*)(ws + MD * 8);
  long off = MD * 10;
  f16* Wt  = (f16*)(ws + off); off += 3L * D_DIM * D_DIM * 2;   // Wyt,Wxt,Wot contiguous
  f16* igagt = (f16*)(ws + off); off += 20L * DH * DH * 2;      // igt(10) then agt(10)
  float* Ac = (float*)(ws + off); off += (long)B_DIM * CHUNKS * D_DIM * 4;
  float* Sc = (float*)(ws + off); off += (long)B_DIM * CHUNKS * D_DIM * 4;
  float* He = (float*)(ws + off); off += (long)B_DIM * CHUNKS * D_DIM * 4;
  f16* Wyt = Wt;
  f16* Wxt = Wt + (long)D_DIM * D_DIM;
  f16* Wot = Wt + 2L * D_DIM * D_DIM;
  f16* igt = igagt;
  f16* agt = igagt + 10L * DH * DH;

  dim3 tb(32, 8);
  // 1. x -> f16
  cvt_f16_kernel<<<dim3((unsigned)(MD / 4 / 256)), 256, 0, stream>>>(x, x16, MD / 4);
  // 2. weight transposes -> [N,K] f16
  transpose_cvt3_kernel<<<dim3(80, 80, 3), tb, 0, stream>>>(Wy, Wx, Wo, Wt, D_DIM, D_DIM);
  transpose_cvt2_kernel<<<dim3(8, 8, 20), tb, 0, stream>>>(igw, agw, igagt, DH, DH, 10);
  // 3. y = gelu(x @ Wy + by) -> f16   (256^2 pipelined GEMM)
  gemm256_kernel<1, 1><<<dim3(10, 64, 1), 512, 0, stream>>>(
      x16, D_DIM, Wyt, D_DIM, by, (void*)y16, D_DIM, D_DIM);
  // 4. xb = x @ Wx + bx -> f16
  gemm256_kernel<0, 1><<<dim3(10, 64, 1), 512, 0, stream>>>(
      x16, D_DIM, Wxt, D_DIM, bx, (void*)xb2, D_DIM, D_DIM);
  // 5. causal conv -> f16
  conv_kernel<<<dim3(5, 4096, 4), 128, 0, stream>>>(xb2, cw, cb, conv16);
  // 6. gate_x = sigmoid(blockdiag(conv)) -> f16
  gemm_kernel<2, 1><<<dim3(2, 128, 10), 256, 0, stream>>>(
      conv16, D_DIM, DH, igt, (long)DH * DH, igb, DH, (void*)gx16, D_DIM, DH, DH,
      nullptr, nullptr, nullptr, nullptr, nullptr);
  // 7. gate_a GEMM + fused RG-LRU elementwise -> a16, nx16
  gemm_kernel<3, 1><<<dim3(2, 128, 10), 256, 0, stream>>>(
      conv16, D_DIM, DH, agt, (long)DH * DH, agb, DH, (void*)a16, D_DIM, DH, DH,
      conv16, gx16, ap, segp, nx16);
  // 8. chunked scan; phase C fuses h*y -> f16
  scanA_kernel<<<dim3(5, CHUNKS, 4), 256, 0, stream>>>(a16, nx16, Ac, Sc);
  scanB_kernel<<<dim3(10, 1, 4), 256, 0, stream>>>(Ac, Sc, He);
  scanC_kernel<<<dim3(5, CHUNKS, 4), 256, 0, stream>>>(a16, nx16, He, y16, hy16);
  // 9. out = (h*y) @ Wo + bo -> f32
  gemm256_kernel<0, 0><<<dim3(10, 64, 1), 512, 0, stream>>>(
      hy16, D_DIM, Wot, D_DIM, bo, (void*)out, D_DIM, D_DIM);
}

// Round 2
// 1357.553 us; speedup vs baseline: 1.0864x; 1.0864x over previous
//
#include <hip/hip_runtime.h>

#define D_DIM 2560
#define T_DIM 4096
#define B_DIM 4
#define H_DIM 10
#define DH 256
#define TW_DIM 4
#define M_DIM (B_DIM * T_DIM)   // 16384
#define CHUNKS 64
#define TC (T_DIM / CHUNKS)     // 64

typedef _Float16 f16;
typedef __attribute__((ext_vector_type(8))) _Float16 f16x8;
typedef __attribute__((ext_vector_type(4))) _Float16 f16x4;
typedef __attribute__((ext_vector_type(2))) _Float16 f16x2;
typedef __attribute__((ext_vector_type(4))) float f32x4;
typedef __attribute__((ext_vector_type(2))) float f32x2;

// ---------------- convert f32 -> f16 (vectorized x4) ----------------
__global__ void cvt_f16_kernel(const float* __restrict__ in, f16* __restrict__ out, long n4) {
  long i = (long)blockIdx.x * blockDim.x + threadIdx.x;
  if (i >= n4) return;
  f32x4 v = ((const f32x4*)in)[i];
  f16x4 o;
  o[0] = (f16)v[0]; o[1] = (f16)v[1]; o[2] = (f16)v[2]; o[3] = (f16)v[3];
  ((f16x4*)out)[i] = o;
}

// ---------------- transpose + convert, 3 separate square sources ----------------
__global__ void transpose_cvt3_kernel(const float* __restrict__ s0, const float* __restrict__ s1,
                                      const float* __restrict__ s2, f16* __restrict__ out,
                                      int R, int C) {
  __shared__ float tile[32][33];
  const int z = blockIdx.z;
  const float* in = (z == 0) ? s0 : ((z == 1) ? s1 : s2);
  out += (long)z * R * C;
  int c0 = blockIdx.x * 32, r0 = blockIdx.y * 32;
  int tx = threadIdx.x, ty = threadIdx.y;
  for (int i = ty; i < 32; i += 8)
    tile[i][tx] = in[(long)(r0 + i) * C + (c0 + tx)];
  __syncthreads();
  for (int i = ty; i < 32; i += 8)
    out[(long)(c0 + i) * R + (r0 + tx)] = (f16)tile[tx][i];
}

// ---------------- transpose + convert, 2 batched sources (ig, ag) ----------------
__global__ void transpose_cvt2_kernel(const float* __restrict__ sa, const float* __restrict__ sb,
                                      f16* __restrict__ out, int R, int C, int half) {
  __shared__ float tile[32][33];
  const int z = blockIdx.z;
  const float* in = (z < half) ? (sa + (long)z * R * C) : (sb + (long)(z - half) * R * C);
  out += (long)z * R * C;
  int c0 = blockIdx.x * 32, r0 = blockIdx.y * 32;
  int tx = threadIdx.x, ty = threadIdx.y;
  for (int i = ty; i < 32; i += 8)
    tile[i][tx] = in[(long)(r0 + i) * C + (c0 + tx)];
  __syncthreads();
  for (int i = ty; i < 32; i += 8)
    out[(long)(c0 + i) * R + (r0 + tx)] = (f16)tile[tx][i];
}

// ---------------- async global -> LDS, 16B per lane ----------------
__device__ __forceinline__ void async_cp16(const void* g, void* l) {
  __builtin_amdgcn_global_load_lds(
      (const __attribute__((address_space(1))) unsigned int*)g,
      (__attribute__((address_space(3))) unsigned int*)l, 16, 0, 0);
}

__device__ __forceinline__ float fast_sigmoid(float v) {
  return 1.f / (1.f + __expf(-v));
}

// =====================================================================
// 256x256 tile, BK=32, 4-deep LDS ring, counted vmcnt(8), 1 barrier per
// K-tile, setprio around MFMA clusters. 512 threads = 8 waves (2x4),
// per-wave 128x64 output (acc[8][4]). LDS = 4 * 32KB = 128 KiB.
//
// Swizzle (R2 fix): LDS row = 64B = banks 16*(row&1) + 4*chunk.
//   chunk_store = (lane&3) ^ swz(row), chunk_read = quad ^ swz(row),
//   swz(r) = ((r&3) ^ ((r>>2)&3)).  Within a quarter-wave this puts
//   exactly 2 lanes per 4-bank group (2-way = free, m136) instead of the
//   previous 4-way ((r&3)-only swizzle collided quad with row&3).
//   Involution on both sides (store pre-swizzles the GLOBAL source since
//   global_load_lds writes linearly; read compensates identically).
//
// XCD swizzle (T1): nwg=640 ≡ 0 mod 8, chunked bijective remap so each
// XCD's L2 sees 8 consecutive M-rows x all 10 N-cols (A-panel reuse).
// =====================================================================
#define BM2 256
#define BN2 256
#define BK2 32

template<int ACT, int OUT16>
__global__ __launch_bounds__(512, 2)
void gemm256_kernel(const f16* __restrict__ A, long ldA,
                    const f16* __restrict__ Bt, long ldB,
                    const float* __restrict__ bias,
                    void* __restrict__ Cv, long ldC, int K) {
  __shared__ __attribute__((aligned(16))) f16 sm[4 * 16384];
  const int tid = threadIdx.x;
  const int wave = tid >> 6;
  const int lane = tid & 63;
  const int wm = wave >> 2;      // 0..1 -> rows wm*128..+127
  const int wn = wave & 3;       // 0..3 -> cols wn*64..+63

  // ---- XCD-aware chunked block remap (grid x=10, y=64 -> 640 wgs)
  const int nx_ = gridDim.x;
  const int nwg = nx_ * gridDim.y;
  int lid = blockIdx.y * nx_ + blockIdx.x;
  lid = (lid & 7) * (nwg >> 3) + (lid >> 3);
  const long bm = (long)(lid / nx_) * BM2;
  const long bn = (long)(lid % nx_) * BN2;

  // ---- staging geometry: unit = 128 rows x 64B (8KB); wave covers 16 rows
  const int sRow = wave * 16 + (lane >> 2);            // row within unit
  const int sChunk = (lane & 3) ^ ((lane >> 2) & 3) ^ ((lane >> 4) & 3);
  const int sOff = sChunk * 8;                          // halfs
  const f16* pA0 = A + (bm + sRow) * ldA + sOff;        // rows 0..127
  const f16* pA1 = pA0 + 128 * ldA;                     // rows 128..255
  const f16* pB0 = Bt + (bn + sRow) * ldB + sOff;
  const f16* pB1 = pB0 + 128 * ldB;
  const int wOff = wave * 512;                          // halfs within unit

  // ---- fragment-read geometry (reader compensates store swizzle)
  const int quad = lane >> 4, l16 = lane & 15;
  const int rswz = (quad ^ (l16 & 3) ^ ((l16 >> 2) & 3)) * 8;
  const int aRowBase = (wm * 128 + l16) * BK2 + rswz;   // + i*16*BK2
  const int bRowBase = (wn * 64 + l16) * BK2 + rswz;    // + j*16*BK2

  f32x4 acc[8][4];
#pragma unroll
  for (int i = 0; i < 8; ++i)
#pragma unroll
    for (int j = 0; j < 4; ++j) {
      acc[i][j][0] = 0.f; acc[i][j][1] = 0.f; acc[i][j][2] = 0.f; acc[i][j][3] = 0.f;
    }

  const int NT = K / BK2;

  // ---- prologue: stage tiles 0,1,2 (12 calls/thread), land tile 0
#pragma unroll
  for (int p = 0; p < 3; ++p) {
    f16* dst = sm + p * 16384;
    const int kp = (p < NT ? p : NT - 1) * BK2;
    async_cp16(pA0 + kp, dst + wOff);
    async_cp16(pA1 + kp, dst + 4096 + wOff);
    async_cp16(pB0 + kp, dst + 8192 + wOff);
    async_cp16(pB1 + kp, dst + 12288 + wOff);
  }
  asm volatile("s_waitcnt vmcnt(8)" ::: "memory");  // tile 0 resident
  __builtin_amdgcn_s_barrier();

  // ---- main loop: 2 phases per K-tile, 16 MFMA each
#pragma unroll 4
  for (int t = 0; t < NT; ++t) {
    const f16* As = sm + (t & 3) * 16384;
    const f16* Bs = As + 8192;
    const int kp = (t + 3 < NT ? t + 3 : NT - 1) * BK2;   // clamped prefetch
    f16* dst = sm + ((t + 3) & 3) * 16384;

    // phase 0: rows wm*128+0..63
    f16x8 af0[4], bf[4];
#pragma unroll
    for (int i = 0; i < 4; ++i) af0[i] = *(const f16x8*)&As[aRowBase + i * 16 * BK2];
#pragma unroll
    for (int j = 0; j < 4; ++j) bf[j]  = *(const f16x8*)&Bs[bRowBase + j * 16 * BK2];
    async_cp16(pA0 + kp, dst + wOff);
    async_cp16(pA1 + kp, dst + 4096 + wOff);
    __builtin_amdgcn_s_setprio(1);
#pragma unroll
    for (int i = 0; i < 4; ++i)
#pragma unroll
      for (int j = 0; j < 4; ++j)
        acc[i][j] = __builtin_amdgcn_mfma_f32_16x16x32_f16(af0[i], bf[j], acc[i][j], 0, 0, 0);
    __builtin_amdgcn_s_setprio(0);

    // phase 1: rows wm*128+64..127 (bf reused)
    f16x8 af1[4];
#pragma unroll
    for (int i = 0; i < 4; ++i) af1[i] = *(const f16x8*)&As[aRowBase + (64 + i * 16) * BK2];
    async_cp16(pB0 + kp, dst + 8192 + wOff);
    async_cp16(pB1 + kp, dst + 12288 + wOff);
    __builtin_amdgcn_s_setprio(1);
#pragma unroll
    for (int i = 0; i < 4; ++i)
#pragma unroll
      for (int j = 0; j < 4; ++j)
        acc[4 + i][j] = __builtin_amdgcn_mfma_f32_16x16x32_f16(af1[i], bf[j], acc[4 + i][j], 0, 0, 0);
    __builtin_amdgcn_s_setprio(0);

    asm volatile("s_waitcnt vmcnt(8)" ::: "memory");  // tile t+1 resident
    __builtin_amdgcn_s_barrier();
  }

  // ---- epilogue: C/D layout col=lane&15, row=(lane>>4)*4+reg
#pragma unroll
  for (int i = 0; i < 8; ++i) {
    const long row0 = bm + wm * 128 + i * 16 + quad * 4;
#pragma unroll
    for (int j = 0; j < 4; ++j) {
      const long colIn = bn + wn * 64 + j * 16 + l16;
      const float bv = bias[colIn];
#pragma unroll
      for (int r = 0; r < 4; ++r) {
        const long row = row0 + r;
        float v = acc[i][j][r] + bv;
        if (ACT == 1) {
          const float u = v;
          const float tt = 0.7978845608028654f * (u + 0.044715f * u * u * u);
          v = u * fast_sigmoid(2.f * tt);   // gelu tanh approx
        }
        const long cidx = row * ldC + colIn;
        if (OUT16) ((f16*)Cv)[cidx] = (f16)v;
        else       ((float*)Cv)[cidx] = v;
      }
    }
  }
}

// =====================================================================
// Fused gate GEMMs: P = sigmoid(conv @ igt + igb), Q = sigmoid(conv @ agt
// + agb), then full RG-LRU elementwise -> a16, nx16.  One A pass, no gx16
// round-trip.  128x128 tile, K=256, two accumulator banks.
// =====================================================================
#define BM 128
#define BN 128
#define BK 32

__global__ __launch_bounds__(256, 2)
void gemm_gates_kernel(const f16* __restrict__ A, long ldA,
                       const f16* __restrict__ igt, const f16* __restrict__ agt,
                       const float* __restrict__ igb, const float* __restrict__ agb,
                       const float* __restrict__ apar, const int* __restrict__ segp,
                       f16* __restrict__ aOut, f16* __restrict__ nxOut, int K) {
  __shared__ __attribute__((aligned(16))) f16 As[BM * BK];
  __shared__ __attribute__((aligned(16))) f16 B1s[BN * BK];
  __shared__ __attribute__((aligned(16))) f16 B2s[BN * BK];
  const int tid = threadIdx.x;
  const int wave = tid >> 6;
  const int lane = tid & 63;
  const int wm = wave >> 1, wn = wave & 1;
  const long bm = (long)blockIdx.y * BM;
  const long bn = (long)blockIdx.x * BN;
  const int z = blockIdx.z;
  const f16* Az = A + (long)z * DH;                  // column offset into [M,D]
  const f16* B1 = igt + (long)z * DH * DH;
  const f16* B2 = agt + (long)z * DH * DH;
  const float* b1 = igb + (long)z * DH;
  const float* b2 = agb + (long)z * DH;
  const long cColOff = (long)z * DH;

  const int sRow = wave * 32 + (lane >> 2);
  const int sCol = ((lane & 3) ^ (sRow & 3) ^ ((sRow >> 2) & 3)) * 8;  // halfs
  const f16* gA = Az + (bm + sRow) * ldA + sCol;
  const f16* gB1 = B1 + (bn + sRow) * (long)K + sCol;
  const f16* gB2 = B2 + (bn + sRow) * (long)K + sCol;
  f16* lA = As + wave * 1024;
  f16* lB1 = B1s + wave * 1024;
  f16* lB2 = B2s + wave * 1024;

  f32x4 accI[4][4], accA[4][4];
#pragma unroll
  for (int i = 0; i < 4; ++i)
#pragma unroll
    for (int j = 0; j < 4; ++j) {
      accI[i][j][0] = 0.f; accI[i][j][1] = 0.f; accI[i][j][2] = 0.f; accI[i][j][3] = 0.f;
      accA[i][j][0] = 0.f; accA[i][j][1] = 0.f; accA[i][j][2] = 0.f; accA[i][j][3] = 0.f;
    }

  const int quad = lane >> 4, l16 = lane & 15;
  const int rswz = (quad ^ (l16 & 3) ^ ((l16 >> 2) & 3)) * 8;

  for (int k0 = 0; k0 < K; k0 += BK) {
    async_cp16(gA, lA);
    async_cp16(gA + 16 * ldA, lA + 512);
    async_cp16(gB1, lB1);
    async_cp16(gB1 + 16 * (long)K, lB1 + 512);
    async_cp16(gB2, lB2);
    async_cp16(gB2 + 16 * (long)K, lB2 + 512);
    gA += BK; gB1 += BK; gB2 += BK;
    __syncthreads();
    f16x8 af[4], bf1[4], bf2[4];
#pragma unroll
    for (int i = 0; i < 4; ++i) {
      af[i]  = *(const f16x8*)&As[(wm * 64 + i * 16 + l16) * BK + rswz];
      bf1[i] = *(const f16x8*)&B1s[(wn * 64 + i * 16 + l16) * BK + rswz];
      bf2[i] = *(const f16x8*)&B2s[(wn * 64 + i * 16 + l16) * BK + rswz];
    }
#pragma unroll
    for (int i = 0; i < 4; ++i)
#pragma unroll
      for (int j = 0; j < 4; ++j) {
        accI[i][j] = __builtin_amdgcn_mfma_f32_16x16x32_f16(af[i], bf1[j], accI[i][j], 0, 0, 0);
        accA[i][j] = __builtin_amdgcn_mfma_f32_16x16x32_f16(af[i], bf2[j], accA[i][j], 0, 0, 0);
      }
    __syncthreads();
  }

  // epilogue: both gates in registers -> RG-LRU, write a16 + nx16
#pragma unroll
  for (int i = 0; i < 4; ++i) {
    const long row0 = bm + wm * 64 + i * 16 + quad * 4;
#pragma unroll
    for (int j = 0; j < 4; ++j) {
      const long colIn = bn + wn * 64 + j * 16 + l16;
      const long colG = cColOff + colIn;
      const float bv1 = b1[colIn];
      const float bv2 = b2[colIn];
      const float sp = log1pf(__expf(apar[colG]));
#pragma unroll
      for (int r = 0; r < 4; ++r) {
        const long row = row0 + r;
        const float gx = fast_sigmoid(accI[i][j][r] + bv1);
        const float ga = fast_sigmoid(accA[i][j][r] + bv2);
        const float log_a = -8.f * ga * sp;
        float a = __expf(log_a);
        float mult = sqrtf(fmaxf(1.f - __expf(2.f * log_a), 0.f));
        if (segp[row] == 0) { a = 0.f; mult = 1.f; }
        const long cidx = row * D_DIM + colG;
        const float cv = (float)A[row * ldA + colG];   // conv value
        aOut[cidx] = (f16)a;
        nxOut[cidx] = (f16)(cv * gx * mult);
      }
    }
  }
}

// ---------------- causal depthwise conv (TW=4), f16 in -> f16 out, x4 ----------------
__global__ void conv_kernel(const f16* __restrict__ xb, const float* __restrict__ cw,
                            const float* __restrict__ cb, f16* __restrict__ out) {
  const int d4 = blockIdx.x * 128 + threadIdx.x;  // over D/4 = 640
  const int t = blockIdx.y;
  const int b = blockIdx.z;
  const long idx4 = ((long)b * T_DIM + t) * (D_DIM / 4) + d4;
  f32x4 acc = ((const f32x4*)cb)[d4];
#pragma unroll
  for (int i = 0; i < TW_DIM; ++i) {
    const int tt = t - (TW_DIM - 1) + i;
    if (tt >= 0) {
      f16x4 xv = ((const f16x4*)xb)[idx4 + (long)(i - (TW_DIM - 1)) * (D_DIM / 4)];
      f32x4 w = ((const f32x4*)cw)[i * (D_DIM / 4) + d4];
      acc[0] += w[0] * (float)xv[0];
      acc[1] += w[1] * (float)xv[1];
      acc[2] += w[2] * (float)xv[2];
      acc[3] += w[3] * (float)xv[3];
    }
  }
  f16x4 o;
  o[0] = (f16)acc[0]; o[1] = (f16)acc[1]; o[2] = (f16)acc[2]; o[3] = (f16)acc[3];
  ((f16x4*)out)[idx4] = o;
}

// ---------------- chunked scan: h_t = a_t h_{t-1} + x_t (x2 vectorized) ----------------
__global__ void scanA_kernel(const f16* __restrict__ a16, const f16* __restrict__ nx16,
                             float* __restrict__ Ac, float* __restrict__ Sc) {
  const int d2 = blockIdx.x * 256 + threadIdx.x;  // over D/2 = 1280
  const int c = blockIdx.y;
  const int b = blockIdx.z;
  long base2 = ((long)b * T_DIM + (long)c * TC) * (D_DIM / 2) + d2;
  float Ap0 = 1.f, Ap1 = 1.f, S0 = 0.f, S1 = 0.f;
  for (int t = 0; t < TC; ++t) {
    f16x2 av = ((const f16x2*)a16)[base2];
    f16x2 xv = ((const f16x2*)nx16)[base2];
    S0 = (float)av[0] * S0 + (float)xv[0];
    S1 = (float)av[1] * S1 + (float)xv[1];
    Ap0 *= (float)av[0];
    Ap1 *= (float)av[1];
    base2 += D_DIM / 2;
  }
  const long cidx2 = ((long)b * CHUNKS + c) * (D_DIM / 2) + d2;
  f32x2 av_; av_[0] = Ap0; av_[1] = Ap1;
  f32x2 sv_; sv_[0] = S0; sv_[1] = S1;
  ((f32x2*)Ac)[cidx2] = av_;
  ((f32x2*)Sc)[cidx2] = sv_;
}

__global__ void scanB_kernel(const float* __restrict__ Ac, const float* __restrict__ Sc,
                             float* __restrict__ He) {
  const int d = blockIdx.x * 256 + threadIdx.x;
  const int b = blockIdx.z;
  float h = 0.f;
  for (int c = 0; c < CHUNKS; ++c) {
    const long cidx = ((long)b * CHUNKS + c) * D_DIM + d;
    He[cidx] = h;  // h at entry of chunk c
    h = Ac[cidx] * h + Sc[cidx];
  }
}

__global__ void scanC_kernel(const f16* __restrict__ a16, const f16* __restrict__ nx16,
                             const float* __restrict__ He, const f16* __restrict__ y16,
                             f16* __restrict__ hy16) {
  const int d2 = blockIdx.x * 256 + threadIdx.x;
  const int c = blockIdx.y;
  const int b = blockIdx.z;
  long base2 = ((long)b * T_DIM + (long)c * TC) * (D_DIM / 2) + d2;
  f32x2 hv = ((const f32x2*)He)[((long)b * CHUNKS + c) * (D_DIM / 2) + d2];
  float h0 = hv[0], h1 = hv[1];
  for (int t = 0; t < TC; ++t) {
    f16x2 av = ((const f16x2*)a16)[base2];
    f16x2 xv = ((const f16x2*)nx16)[base2];
    f16x2 yv = ((const f16x2*)y16)[base2];
    h0 = (float)av[0] * h0 + (float)xv[0];
    h1 = (float)av[1] * h1 + (float)xv[1];
    f16x2 o;
    o[0] = (f16)(h0 * (float)yv[0]);
    o[1] = (f16)(h1 * (float)yv[1]);
    ((f16x2*)hy16)[base2] = o;
    base2 += D_DIM / 2;
  }
}

// ---------------- launch ----------------
extern "C" void kernel_launch(void* const* d_in, const int* in_sizes, int n_in,
                              void* d_out, int out_size, void* d_ws, size_t ws_size,
                              hipStream_t stream) {
  const float* x   = (const float*)d_in[0];
  const int*   segp= (const int*)d_in[1];
  const float* Wy  = (const float*)d_in[2];
  const float* by  = (const float*)d_in[3];
  const float* Wx  = (const float*)d_in[4];
  const float* bx  = (const float*)d_in[5];
  const float* cw  = (const float*)d_in[6];
  const float* cb  = (const float*)d_in[7];
  const float* ap  = (const float*)d_in[8];
  const float* igw = (const float*)d_in[9];
  const float* igb = (const float*)d_in[10];
  const float* agw = (const float*)d_in[11];
  const float* agb = (const float*)d_in[12];
  const float* Wo  = (const float*)d_in[13];
  const float* bo  = (const float*)d_in[14];
  float* out = (float*)d_out;
  char* ws = (char*)d_ws;

  const long MD = (long)M_DIM * D_DIM;  // 41,943,040
  f16*   x16    = (f16*)(ws + 0);          // dead after GEMMs 1,2 -> a16
  f16*   a16    = (f16*)(ws + 0);
  f16*   y16    = (f16*)(ws + MD * 2);     // live until scanC
  f16*   xb2    = (f16*)(ws + MD * 4);     // dead after conv -> hy16
  f16*   hy16   = (f16*)(ws + MD * 4);
  f16*   conv16 = (f16*)(ws + MD * 6);     // live until gates epilogue
  f16*   nx16   = (f16*)(ws + MD * 8);
  long off = MD * 10;
  f16* Wt  = (f16*)(ws + off); off += 3L * D_DIM * D_DIM * 2;   // Wyt,Wxt,Wot contiguous
  f16* igagt = (f16*)(ws + off); off += 20L * DH * DH * 2;      // igt(10) then agt(10)
  float* Ac = (float*)(ws + off); off += (long)B_DIM * CHUNKS * D_DIM * 4;
  float* Sc = (float*)(ws + off); off += (long)B_DIM * CHUNKS * D_DIM * 4;
  float* He = (float*)(ws + off); off += (long)B_DIM * CHUNKS * D_DIM * 4;
  f16* Wyt = Wt;
  f16* Wxt = Wt + (long)D_DIM * D_DIM;
  f16* Wot = Wt + 2L * D_DIM * D_DIM;
  f16* igt = igagt;
  f16* agt = igagt + 10L * DH * DH;

  dim3 tb(32, 8);
  // 1. x -> f16
  cvt_f16_kernel<<<dim3((unsigned)(MD / 4 / 256)), 256, 0, stream>>>(x, x16, MD / 4);
  // 2. weight transposes -> [N,K] f16
  transpose_cvt3_kernel<<<dim3(80, 80, 3), tb, 0, stream>>>(Wy, Wx, Wo, Wt, D_DIM, D_DIM);
  transpose_cvt2_kernel<<<dim3(8, 8, 20), tb, 0, stream>>>(igw, agw, igagt, DH, DH, 10);
  // 3. y = gelu(x @ Wy + by) -> f16   (256^2 pipelined GEMM)
  gemm256_kernel<1, 1><<<dim3(10, 64, 1), 512, 0, stream>>>(
      x16, D_DIM, Wyt, D_DIM, by, (void*)y16, D_DIM, D_DIM);
  // 4. xb = x @ Wx + bx -> f16
  gemm256_kernel<0, 1><<<dim3(10, 64, 1), 512, 0, stream>>>(
      x16, D_DIM, Wxt, D_DIM, bx, (void*)xb2, D_DIM, D_DIM);
  // 5. causal conv -> f16
  conv_kernel<<<dim3(5, 4096, 4), 128, 0, stream>>>(xb2, cw, cb, conv16);
  // 6+7. fused gate GEMMs + RG-LRU elementwise -> a16, nx16
  gemm_gates_kernel<<<dim3(2, 128, 10), 256, 0, stream>>>(
      conv16, D_DIM, igt, agt, igb, agb, ap, segp, a16, nx16, DH);
  // 8. chunked scan; phase C fuses h*y -> f16
  scanA_kernel<<<dim3(5, CHUNKS, 4), 256, 0, stream>>>(a16, nx16, Ac, Sc);
  scanB_kernel<<<dim3(10, 1, 4), 256, 0, stream>>>(Ac, Sc, He);
  scanC_kernel<<<dim3(5, CHUNKS, 4), 256, 0, stream>>>(a16, nx16, He, y16, hy16);
  // 9. out = (h*y) @ Wo + bo -> f32
  gemm256_kernel<0, 0><<<dim3(10, 64, 1), 512, 0, stream>>>(
      hy16, D_DIM, Wot, D_DIM, bo, (void*)out, D_DIM, D_DIM);
}

// Round 4
// 1344.047 us; speedup vs baseline: 1.0974x; 1.0100x over previous
//
#include <hip/hip_runtime.h>

#define D_DIM 2560
#define T_DIM 4096
#define B_DIM 4
#define H_DIM 10
#define DH 256
#define TW_DIM 4
#define M_DIM (B_DIM * T_DIM)   // 16384
#define CHUNKS 64
#define TC (T_DIM / CHUNKS)     // 64

typedef _Float16 f16;
typedef __attribute__((ext_vector_type(8))) _Float16 f16x8;
typedef __attribute__((ext_vector_type(4))) _Float16 f16x4;
typedef __attribute__((ext_vector_type(2))) _Float16 f16x2;
typedef __attribute__((ext_vector_type(4))) float f32x4;
typedef __attribute__((ext_vector_type(2))) float f32x2;

// ---------------- convert f32 -> f16 (vectorized x4) ----------------
__global__ void cvt_f16_kernel(const float* __restrict__ in, f16* __restrict__ out, long n4) {
  long i = (long)blockIdx.x * blockDim.x + threadIdx.x;
  if (i >= n4) return;
  f32x4 v = ((const f32x4*)in)[i];
  f16x4 o;
  o[0] = (f16)v[0]; o[1] = (f16)v[1]; o[2] = (f16)v[2]; o[3] = (f16)v[3];
  ((f16x4*)out)[i] = o;
}

// ---------------- transpose + convert, 3 separate square sources ----------------
__global__ void transpose_cvt3_kernel(const float* __restrict__ s0, const float* __restrict__ s1,
                                      const float* __restrict__ s2, f16* __restrict__ out,
                                      int R, int C) {
  __shared__ float tile[32][33];
  const int z = blockIdx.z;
  const float* in = (z == 0) ? s0 : ((z == 1) ? s1 : s2);
  out += (long)z * R * C;
  int c0 = blockIdx.x * 32, r0 = blockIdx.y * 32;
  int tx = threadIdx.x, ty = threadIdx.y;
  for (int i = ty; i < 32; i += 8)
    tile[i][tx] = in[(long)(r0 + i) * C + (c0 + tx)];
  __syncthreads();
  for (int i = ty; i < 32; i += 8)
    out[(long)(c0 + i) * R + (r0 + tx)] = (f16)tile[tx][i];
}

// ---------------- transpose + convert, 2 batched sources (ig, ag) ----------------
__global__ void transpose_cvt2_kernel(const float* __restrict__ sa, const float* __restrict__ sb,
                                      f16* __restrict__ out, int R, int C, int half) {
  __shared__ float tile[32][33];
  const int z = blockIdx.z;
  const float* in = (z < half) ? (sa + (long)z * R * C) : (sb + (long)(z - half) * R * C);
  out += (long)z * R * C;
  int c0 = blockIdx.x * 32, r0 = blockIdx.y * 32;
  int tx = threadIdx.x, ty = threadIdx.y;
  for (int i = ty; i < 32; i += 8)
    tile[i][tx] = in[(long)(r0 + i) * C + (c0 + tx)];
  __syncthreads();
  for (int i = ty; i < 32; i += 8)
    out[(long)(c0 + i) * R + (r0 + tx)] = (f16)tile[tx][i];
}

// ---------------- async global -> LDS, 16B per lane ----------------
__device__ __forceinline__ void async_cp16(const void* g, void* l) {
  __builtin_amdgcn_global_load_lds(
      (const __attribute__((address_space(1))) unsigned int*)g,
      (__attribute__((address_space(3))) unsigned int*)l, 16, 0, 0);
}

__device__ __forceinline__ float fast_sigmoid(float v) {
  return 1.f / (1.f + __expf(-v));
}

// =====================================================================
// 8-phase 256x256 GEMM (m201-style). BK=64, 2 buffers (even K-step->buf0,
// odd->buf1), LDS 128KiB. 8 waves (2M x 4N), per-wave 128x64 (acc[8][4]).
// Per iteration = 2 K-steps = 8 phases; each phase: {ds_read quadrant regs,
// stage 1 half-tile (2 global_load_lds), barrier, lgkmcnt(0), setprio,
// 16 MFMA, setprio, [vmcnt(4) at ph4/ph8], barrier}.
//
// LDS halfs layout: buf*32768 + {A0:0, A1:8192, B0:16384, B1:24576} +
// row*64 + chunk*8, with chunk XOR-swizzle: LDS[r][c] = G[r][c ^ (r&7)]
// (store swizzles the per-lane GLOBAL address; gload_lds dest is linear).
// Read compensates: chunk = (4h + quad) ^ (l16&7) -> even bank spread at
// every lane granularity.
//
// Stage schedule (iter i, s=2i):  deaths: B(s) after ph2, A(s) after ph3,
//   B(s+1) after ph6, A(s+1) after ph7 (reads: q0=A_lo+B_lo, q1=B_hi,
//   q2=A_hi, q3=regs only).
//   ph1: A0(s+1)->buf1   ph2: A1(s+1)->buf1   ph3: B0(s+2)->buf0
//   ph4: B1(s+2)->buf0   ph5: A0(s+2)->buf0   ph6: A1(s+2)->buf0
//   ph7: B0(s+3)->buf1   ph8: B1(s+3)->buf1
// vmcnt(4) (= last 2 stages may be outstanding) at END of ph4 and ph8,
// before the barrier: every half-tile retires >=1 vmcnt+barrier before
// its first read (prologue + clamped tail verified by ledger).
// =====================================================================
#define BM2 256
#define BN2 256

template<int ACT, int OUT16>
__global__ __launch_bounds__(512, 2)
void gemm256_kernel(const f16* __restrict__ A, long ldA,
                    const f16* __restrict__ Bt, long ldB,
                    const float* __restrict__ bias,
                    void* __restrict__ Cv, long ldC, int K) {
  __shared__ __attribute__((aligned(16))) f16 smh[65536];  // 128 KiB
  const int tid = threadIdx.x;
  const int wave = tid >> 6;
  const int lane = tid & 63;
  const int wm = wave >> 2;      // 0..1 -> rows wm*128..+127
  const int wn = wave & 3;       // 0..3 -> cols wn*64..+63

  // ---- XCD-aware chunked block remap (640 wgs, 640%8==0)
  const int nx_ = gridDim.x;
  const int nwg = nx_ * gridDim.y;
  int lid = blockIdx.y * nx_ + blockIdx.x;
  lid = (lid & 7) * (nwg >> 3) + (lid >> 3);
  const long bm = (long)(lid / nx_) * BM2;
  const long bn = (long)(lid % nx_) * BN2;

  // ---- staging geometry: instr covers 8 rows x 128B; wave w covers rows 16w..16w+15 (2 instr)
  const int rsub = lane >> 3;                     // 0..7
  const int gc8 = (((lane & 7) ^ rsub) & 7) * 8;  // swizzled global 16B-chunk (halfs)
  const f16* gA0 = A + (bm + wave * 16 + rsub) * ldA + gc8;
  const f16* gB0 = Bt + (bn + wave * 16 + rsub) * ldB + gc8;
  const int wls = wave * 1024;                    // lds halfs within half-tile

#define STG_A(buf, al, ko) do { \
  async_cp16(gA0 + ((al) * 128) * ldA + (ko), smh + (buf) * 32768 + (al) * 8192 + wls); \
  async_cp16(gA0 + ((al) * 128 + 8) * ldA + (ko), smh + (buf) * 32768 + (al) * 8192 + wls + 512); \
} while (0)
#define STG_B(buf, bl, ko) do { \
  async_cp16(gB0 + ((bl) * 128) * ldB + (ko), smh + (buf) * 32768 + 16384 + (bl) * 8192 + wls); \
  async_cp16(gB0 + ((bl) * 128 + 8) * ldB + (ko), smh + (buf) * 32768 + 16384 + (bl) * 8192 + wls + 512); \
} while (0)

  // ---- fragment-read geometry
  const int quad = lane >> 4, l16 = lane & 15;
  const int sw0 = ((quad ^ (l16 & 7)) & 7) * 8;        // h=0 chunk (halfs)
  const int sw1 = (((4 + quad) ^ (l16 & 7)) & 7) * 8;  // h=1 chunk
  const int aRB0 = wm * 8192 + l16 * 64;
  const int aRB1 = 32768 + aRB0;
  const int bRB0 = 16384 + (wn >> 1) * 8192 + ((wn & 1) * 64 + l16) * 64;
  const int bRB1 = 32768 + bRB0;

  f16x8 aF[4][2], bF[4][2];
  f32x4 acc[8][4];
#pragma unroll
  for (int i = 0; i < 8; ++i)
#pragma unroll
    for (int j = 0; j < 4; ++j) {
      acc[i][j][0] = 0.f; acc[i][j][1] = 0.f; acc[i][j][2] = 0.f; acc[i][j][3] = 0.f;
    }

#define RD_AQ(base, off) do { _Pragma("unroll") for (int m_ = 0; m_ < 4; ++m_) { \
  aF[m_][0] = *(const f16x8*)&smh[(base) + (off) + m_ * 1024 + sw0]; \
  aF[m_][1] = *(const f16x8*)&smh[(base) + (off) + m_ * 1024 + sw1]; } } while (0)
#define RD_B2(base, n0) do { _Pragma("unroll") for (int n_ = 0; n_ < 2; ++n_) { \
  bF[(n0) + n_][0] = *(const f16x8*)&smh[(base) + ((n0) + n_) * 1024 + sw0]; \
  bF[(n0) + n_][1] = *(const f16x8*)&smh[(base) + ((n0) + n_) * 1024 + sw1]; } } while (0)
#define MMQ(m0, n0) do { _Pragma("unroll") for (int m_ = 0; m_ < 4; ++m_) \
  _Pragma("unroll") for (int n_ = 0; n_ < 2; ++n_) \
    acc[(m0) + m_][(n0) + n_] = __builtin_amdgcn_mfma_f32_16x16x32_f16(aF[m_][1], bF[(n0) + n_][1], \
      __builtin_amdgcn_mfma_f32_16x16x32_f16(aF[m_][0], bF[(n0) + n_][0], acc[(m0) + m_][(n0) + n_], 0, 0, 0), 0, 0, 0); \
} while (0)
#define PH_MID() \
  __builtin_amdgcn_s_barrier(); \
  asm volatile("s_waitcnt lgkmcnt(0)" ::: "memory"); \
  __builtin_amdgcn_sched_barrier(0); \
  __builtin_amdgcn_s_setprio(1)
#define PH_END() \
  __builtin_amdgcn_s_setprio(0); \
  __builtin_amdgcn_s_barrier(); \
  __builtin_amdgcn_sched_barrier(0)
#define PH_END_VM() \
  __builtin_amdgcn_s_setprio(0); \
  asm volatile("s_waitcnt vmcnt(4)" ::: "memory"); \
  __builtin_amdgcn_s_barrier(); \
  __builtin_amdgcn_sched_barrier(0)

  // ---- prologue: stage (in order) A0(1),A1(1),B0(0),B1(0),A0(0),A1(0),B0(1),B1(1)
  STG_A(1, 0, 64); STG_A(1, 1, 64);
  STG_B(0, 0, 0);  STG_B(0, 1, 0);
  STG_A(0, 0, 0);  STG_A(0, 1, 0);
  STG_B(1, 0, 64); STG_B(1, 1, 64);
  asm volatile("s_waitcnt vmcnt(4)" ::: "memory");
  __builtin_amdgcn_s_barrier();
  __builtin_amdgcn_sched_barrier(0);

  const int NIT = K / 128;   // 20 iterations, 2 K-steps each (K=2560 -> NT=40)
  const int NTm1 = (K / 64) - 1;
#pragma unroll 1
  for (int it = 0; it < NIT; ++it) {
    const long k1 = (long)(2 * it + 1) * 64;                                  // never clamps
    const long k2 = (long)(2 * it + 2 <= NTm1 ? 2 * it + 2 : NTm1) * 64;
    const long k3 = (long)(2 * it + 3 <= NTm1 ? 2 * it + 3 : NTm1) * 64;
    // ph1: q0 (A_lo x B_lo) from buf0; stage A0(s+1)
    RD_AQ(aRB0, 0); RD_B2(bRB0, 0); STG_A(1, 0, k1); PH_MID(); MMQ(0, 0); PH_END();
    // ph2: q1 (A_lo x B_hi); stage A1(s+1)
    RD_B2(bRB0, 2); STG_A(1, 1, k1); PH_MID(); MMQ(0, 2); PH_END();
    // ph3: q2 (A_hi x B_hi); stage B0(s+2)
    RD_AQ(aRB0, 4096); STG_B(0, 0, k2); PH_MID(); MMQ(4, 2); PH_END();
    // ph4: q3 (A_hi x B_lo, regs only); stage B1(s+2); vmcnt
    STG_B(0, 1, k2); PH_MID(); MMQ(4, 0); PH_END_VM();
    // ph5..ph8: K-step s+1 from buf1
    RD_AQ(aRB1, 0); RD_B2(bRB1, 0); STG_A(0, 0, k2); PH_MID(); MMQ(0, 0); PH_END();
    RD_B2(bRB1, 2); STG_A(0, 1, k2); PH_MID(); MMQ(0, 2); PH_END();
    RD_AQ(aRB1, 4096); STG_B(1, 0, k3); PH_MID(); MMQ(4, 2); PH_END();
    STG_B(1, 1, k3); PH_MID(); MMQ(4, 0); PH_END_VM();
  }
  asm volatile("s_waitcnt vmcnt(0)" ::: "memory");

  // ---- epilogue: C/D layout col=lane&15, row=(lane>>4)*4+reg
#pragma unroll
  for (int i = 0; i < 8; ++i) {
    const long row0 = bm + wm * 128 + i * 16 + quad * 4;
#pragma unroll
    for (int j = 0; j < 4; ++j) {
      const long colIn = bn + wn * 64 + j * 16 + l16;
      const float bv = bias[colIn];
#pragma unroll
      for (int r = 0; r < 4; ++r) {
        const long row = row0 + r;
        float v = acc[i][j][r] + bv;
        if (ACT == 1) {
          const float u = v;
          const float tt = 0.7978845608028654f * (u + 0.044715f * u * u * u);
          v = u * fast_sigmoid(2.f * tt);   // gelu tanh approx
        }
        const long cidx = row * ldC + colIn;
        if (OUT16) ((f16*)Cv)[cidx] = (f16)v;
        else       ((float*)Cv)[cidx] = v;
      }
    }
  }
#undef STG_A
#undef STG_B
#undef RD_AQ
#undef RD_B2
#undef MMQ
#undef PH_MID
#undef PH_END
#undef PH_END_VM
}

// =====================================================================
// Fused gate GEMMs: gate_x/gate_a sigmoid + RG-LRU elementwise -> a16, nx16
// =====================================================================
#define BM 128
#define BN 128
#define BK 32

__global__ __launch_bounds__(256, 2)
void gemm_gates_kernel(const f16* __restrict__ A, long ldA,
                       const f16* __restrict__ igt, const f16* __restrict__ agt,
                       const float* __restrict__ igb, const float* __restrict__ agb,
                       const float* __restrict__ apar, const int* __restrict__ segp,
                       f16* __restrict__ aOut, f16* __restrict__ nxOut, int K) {
  __shared__ __attribute__((aligned(16))) f16 As[BM * BK];
  __shared__ __attribute__((aligned(16))) f16 B1s[BN * BK];
  __shared__ __attribute__((aligned(16))) f16 B2s[BN * BK];
  const int tid = threadIdx.x;
  const int wave = tid >> 6;
  const int lane = tid & 63;
  const int wm = wave >> 1, wn = wave & 1;
  const long bm = (long)blockIdx.y * BM;
  const long bn = (long)blockIdx.x * BN;
  const int z = blockIdx.z;
  const f16* Az = A + (long)z * DH;                  // column offset into [M,D]
  const f16* B1 = igt + (long)z * DH * DH;
  const f16* B2 = agt + (long)z * DH * DH;
  const float* b1 = igb + (long)z * DH;
  const float* b2 = agb + (long)z * DH;
  const long cColOff = (long)z * DH;

  const int sRow = wave * 32 + (lane >> 2);
  const int sCol = ((lane & 3) ^ (sRow & 3) ^ ((sRow >> 2) & 3)) * 8;  // halfs
  const f16* gA = Az + (bm + sRow) * ldA + sCol;
  const f16* gB1 = B1 + (bn + sRow) * (long)K + sCol;
  const f16* gB2 = B2 + (bn + sRow) * (long)K + sCol;
  f16* lA = As + wave * 1024;
  f16* lB1 = B1s + wave * 1024;
  f16* lB2 = B2s + wave * 1024;

  f32x4 accI[4][4], accA[4][4];
#pragma unroll
  for (int i = 0; i < 4; ++i)
#pragma unroll
    for (int j = 0; j < 4; ++j) {
      accI[i][j][0] = 0.f; accI[i][j][1] = 0.f; accI[i][j][2] = 0.f; accI[i][j][3] = 0.f;
      accA[i][j][0] = 0.f; accA[i][j][1] = 0.f; accA[i][j][2] = 0.f; accA[i][j][3] = 0.f;
    }

  const int quad = lane >> 4, l16 = lane & 15;
  const int rswz = (quad ^ (l16 & 3) ^ ((l16 >> 2) & 3)) * 8;

  for (int k0 = 0; k0 < K; k0 += BK) {
    async_cp16(gA, lA);
    async_cp16(gA + 16 * ldA, lA + 512);
    async_cp16(gB1, lB1);
    async_cp16(gB1 + 16 * (long)K, lB1 + 512);
    async_cp16(gB2, lB2);
    async_cp16(gB2 + 16 * (long)K, lB2 + 512);
    gA += BK; gB1 += BK; gB2 += BK;
    __syncthreads();
    f16x8 af[4], bf1[4], bf2[4];
#pragma unroll
    for (int i = 0; i < 4; ++i) {
      af[i]  = *(const f16x8*)&As[(wm * 64 + i * 16 + l16) * BK + rswz];
      bf1[i] = *(const f16x8*)&B1s[(wn * 64 + i * 16 + l16) * BK + rswz];
      bf2[i] = *(const f16x8*)&B2s[(wn * 64 + i * 16 + l16) * BK + rswz];
    }
#pragma unroll
    for (int i = 0; i < 4; ++i)
#pragma unroll
      for (int j = 0; j < 4; ++j) {
        accI[i][j] = __builtin_amdgcn_mfma_f32_16x16x32_f16(af[i], bf1[j], accI[i][j], 0, 0, 0);
        accA[i][j] = __builtin_amdgcn_mfma_f32_16x16x32_f16(af[i], bf2[j], accA[i][j], 0, 0, 0);
      }
    __syncthreads();
  }

#pragma unroll
  for (int i = 0; i < 4; ++i) {
    const long row0 = bm + wm * 64 + i * 16 + quad * 4;
#pragma unroll
    for (int j = 0; j < 4; ++j) {
      const long colIn = bn + wn * 64 + j * 16 + l16;
      const long colG = cColOff + colIn;
      const float bv1 = b1[colIn];
      const float bv2 = b2[colIn];
      const float sp = log1pf(__expf(apar[colG]));
#pragma unroll
      for (int r = 0; r < 4; ++r) {
        const long row = row0 + r;
        const float gx = fast_sigmoid(accI[i][j][r] + bv1);
        const float ga = fast_sigmoid(accA[i][j][r] + bv2);
        const float log_a = -8.f * ga * sp;
        float a = __expf(log_a);
        float mult = sqrtf(fmaxf(1.f - __expf(2.f * log_a), 0.f));
        if (segp[row] == 0) { a = 0.f; mult = 1.f; }
        const long cidx = row * D_DIM + colG;
        const float cv = (float)A[row * ldA + colG];   // conv value
        aOut[cidx] = (f16)a;
        nxOut[cidx] = (f16)(cv * gx * mult);
      }
    }
  }
}

// ---------------- causal depthwise conv (TW=4), f16 in -> f16 out, x4 ----------------
__global__ void conv_kernel(const f16* __restrict__ xb, const float* __restrict__ cw,
                            const float* __restrict__ cb, f16* __restrict__ out) {
  const int d4 = blockIdx.x * 128 + threadIdx.x;  // over D/4 = 640
  const int t = blockIdx.y;
  const int b = blockIdx.z;
  const long idx4 = ((long)b * T_DIM + t) * (D_DIM / 4) + d4;
  f32x4 acc = ((const f32x4*)cb)[d4];
#pragma unroll
  for (int i = 0; i < TW_DIM; ++i) {
    const int tt = t - (TW_DIM - 1) + i;
    if (tt >= 0) {
      f16x4 xv = ((const f16x4*)xb)[idx4 + (long)(i - (TW_DIM - 1)) * (D_DIM / 4)];
      f32x4 w = ((const f32x4*)cw)[i * (D_DIM / 4) + d4];
      acc[0] += w[0] * (float)xv[0];
      acc[1] += w[1] * (float)xv[1];
      acc[2] += w[2] * (float)xv[2];
      acc[3] += w[3] * (float)xv[3];
    }
  }
  f16x4 o;
  o[0] = (f16)acc[0]; o[1] = (f16)acc[1]; o[2] = (f16)acc[2]; o[3] = (f16)acc[3];
  ((f16x4*)out)[idx4] = o;
}

// ---------------- chunked scan: h_t = a_t h_{t-1} + x_t (x2 vectorized) ----------------
__global__ void scanA_kernel(const f16* __restrict__ a16, const f16* __restrict__ nx16,
                             float* __restrict__ Ac, float* __restrict__ Sc) {
  const int d2 = blockIdx.x * 256 + threadIdx.x;  // over D/2 = 1280
  const int c = blockIdx.y;
  const int b = blockIdx.z;
  long base2 = ((long)b * T_DIM + (long)c * TC) * (D_DIM / 2) + d2;
  float Ap0 = 1.f, Ap1 = 1.f, S0 = 0.f, S1 = 0.f;
  for (int t = 0; t < TC; ++t) {
    f16x2 av = ((const f16x2*)a16)[base2];
    f16x2 xv = ((const f16x2*)nx16)[base2];
    S0 = (float)av[0] * S0 + (float)xv[0];
    S1 = (float)av[1] * S1 + (float)xv[1];
    Ap0 *= (float)av[0];
    Ap1 *= (float)av[1];
    base2 += D_DIM / 2;
  }
  const long cidx2 = ((long)b * CHUNKS + c) * (D_DIM / 2) + d2;
  f32x2 av_; av_[0] = Ap0; av_[1] = Ap1;
  f32x2 sv_; sv_[0] = S0; sv_[1] = S1;
  ((f32x2*)Ac)[cidx2] = av_;
  ((f32x2*)Sc)[cidx2] = sv_;
}

__global__ void scanB_kernel(const float* __restrict__ Ac, const float* __restrict__ Sc,
                             float* __restrict__ He) {
  const int d = blockIdx.x * 256 + threadIdx.x;
  const int b = blockIdx.z;
  float h = 0.f;
  for (int c = 0; c < CHUNKS; ++c) {
    const long cidx = ((long)b * CHUNKS + c) * D_DIM + d;
    He[cidx] = h;  // h at entry of chunk c
    h = Ac[cidx] * h + Sc[cidx];
  }
}

__global__ void scanC_kernel(const f16* __restrict__ a16, const f16* __restrict__ nx16,
                             const float* __restrict__ He, const f16* __restrict__ y16,
                             f16* __restrict__ hy16) {
  const int d2 = blockIdx.x * 256 + threadIdx.x;
  const int c = blockIdx.y;
  const int b = blockIdx.z;
  long base2 = ((long)b * T_DIM + (long)c * TC) * (D_DIM / 2) + d2;
  f32x2 hv = ((const f32x2*)He)[((long)b * CHUNKS + c) * (D_DIM / 2) + d2];
  float h0 = hv[0], h1 = hv[1];
  for (int t = 0; t < TC; ++t) {
    f16x2 av = ((const f16x2*)a16)[base2];
    f16x2 xv = ((const f16x2*)nx16)[base2];
    f16x2 yv = ((const f16x2*)y16)[base2];
    h0 = (float)av[0] * h0 + (float)xv[0];
    h1 = (float)av[1] * h1 + (float)xv[1];
    f16x2 o;
    o[0] = (f16)(h0 * (float)yv[0]);
    o[1] = (f16)(h1 * (float)yv[1]);
    ((f16x2*)hy16)[base2] = o;
    base2 += D_DIM / 2;
  }
}

// ---------------- launch ----------------
extern "C" void kernel_launch(void* const* d_in, const int* in_sizes, int n_in,
                              void* d_out, int out_size, void* d_ws, size_t ws_size,
                              hipStream_t stream) {
  const float* x   = (const float*)d_in[0];
  const int*   segp= (const int*)d_in[1];
  const float* Wy  = (const float*)d_in[2];
  const float* by  = (const float*)d_in[3];
  const float* Wx  = (const float*)d_in[4];
  const float* bx  = (const float*)d_in[5];
  const float* cw  = (const float*)d_in[6];
  const float* cb  = (const float*)d_in[7];
  const float* ap  = (const float*)d_in[8];
  const float* igw = (const float*)d_in[9];
  const float* igb = (const float*)d_in[10];
  const float* agw = (const float*)d_in[11];
  const float* agb = (const float*)d_in[12];
  const float* Wo  = (const float*)d_in[13];
  const float* bo  = (const float*)d_in[14];
  float* out = (float*)d_out;
  char* ws = (char*)d_ws;

  const long MD = (long)M_DIM * D_DIM;  // 41,943,040
  f16*   x16    = (f16*)(ws + 0);          // dead after GEMMs 1,2 -> a16
  f16*   a16    = (f16*)(ws + 0);
  f16*   y16    = (f16*)(ws + MD * 2);     // live until scanC
  f16*   xb2    = (f16*)(ws + MD * 4);     // dead after conv -> hy16
  f16*   hy16   = (f16*)(ws + MD * 4);
  f16*   conv16 = (f16*)(ws + MD * 6);     // live until gates epilogue
  f16*   nx16   = (f16*)(ws + MD * 8);
  long off = MD * 10;
  f16* Wt  = (f16*)(ws + off); off += 3L * D_DIM * D_DIM * 2;   // Wyt,Wxt,Wot contiguous
  f16* igagt = (f16*)(ws + off); off += 20L * DH * DH * 2;      // igt(10) then agt(10)
  float* Ac = (float*)(ws + off); off += (long)B_DIM * CHUNKS * D_DIM * 4;
  float* Sc = (float*)(ws + off); off += (long)B_DIM * CHUNKS * D_DIM * 4;
  float* He = (float*)(ws + off); off += (long)B_DIM * CHUNKS * D_DIM * 4;
  f16* Wyt = Wt;
  f16* Wxt = Wt + (long)D_DIM * D_DIM;
  f16* Wot = Wt + 2L * D_DIM * D_DIM;
  f16* igt = igagt;
  f16* agt = igagt + 10L * DH * DH;

  dim3 tb(32, 8);
  // 1. x -> f16
  cvt_f16_kernel<<<dim3((unsigned)(MD / 4 / 256)), 256, 0, stream>>>(x, x16, MD / 4);
  // 2. weight transposes -> [N,K] f16
  transpose_cvt3_kernel<<<dim3(80, 80, 3), tb, 0, stream>>>(Wy, Wx, Wo, Wt, D_DIM, D_DIM);
  transpose_cvt2_kernel<<<dim3(8, 8, 20), tb, 0, stream>>>(igw, agw, igagt, DH, DH, 10);
  // 3. y = gelu(x @ Wy + by) -> f16   (8-phase 256^2 GEMM)
  gemm256_kernel<1, 1><<<dim3(10, 64, 1), 512, 0, stream>>>(
      x16, D_DIM, Wyt, D_DIM, by, (void*)y16, D_DIM, D_DIM);
  // 4. xb = x @ Wx + bx -> f16
  gemm256_kernel<0, 1><<<dim3(10, 64, 1), 512, 0, stream>>>(
      x16, D_DIM, Wxt, D_DIM, bx, (void*)xb2, D_DIM, D_DIM);
  // 5. causal conv -> f16
  conv_kernel<<<dim3(5, 4096, 4), 128, 0, stream>>>(xb2, cw, cb, conv16);
  // 6+7. fused gate GEMMs + RG-LRU elementwise -> a16, nx16
  gemm_gates_kernel<<<dim3(2, 128, 10), 256, 0, stream>>>(
      conv16, D_DIM, igt, agt, igb, agb, ap, segp, a16, nx16, DH);
  // 8. chunked scan; phase C fuses h*y -> f16
  scanA_kernel<<<dim3(5, CHUNKS, 4), 256, 0, stream>>>(a16, nx16, Ac, Sc);
  scanB_kernel<<<dim3(10, 1, 4), 256, 0, stream>>>(Ac, Sc, He);
  scanC_kernel<<<dim3(5, CHUNKS, 4), 256, 0, stream>>>(a16, nx16, He, y16, hy16);
  // 9. out = (h*y) @ Wo + bo -> f32
  gemm256_kernel<0, 0><<<dim3(10, 64, 1), 512, 0, stream>>>(
      hy16, D_DIM, Wot, D_DIM, bo, (void*)out, D_DIM, D_DIM);
}